// Round 4
// baseline (142.177 us; speedup 1.0000x reference)
//
#include <hip/hip_runtime.h>

// Linear-superposition AR(p).
// The recurrence pred_t = bias + sum_j a_j * v_{t-12+j} is linear in the
// initial history h0 and bias, and identical across batch b. So:
//   pred[b,t,n] = sum_j W[t,j,n] * h0[b,j,n] + Beta[t,n]
// K1 computes W (12 unit-impulse responses) and Beta per n via the verified
// scatter-form recurrence (round-2 kernel, absmax 1.95e-3).
// K2 applies it fully parallel over (b,t,n) — no serial chain, ~18 waves/CU,
// write-BW bound.

constexpr int B = 64;
constexpr int T = 288;
constexpr int N = 1024;
constexpr int P = 12;
constexpr int BC = 8;   // b-tile per thread in K2
constexpr int TC = 8;   // t-tile per thread in K2

// ---------------- K1: propagate impulse responses ----------------
// thread (seq, n), seq in [0,12]: seq<12 -> column seq of W; seq==12 -> Beta.
// Layouts (lane = n, coalesced): W[t][j][n], Beta[t][n].
__global__ __launch_bounds__(256) void ar_propagate_kernel(
    const float* __restrict__ ar,      // (N, P)
    const float* __restrict__ bias,    // (N,)
    float* __restrict__ W,             // (T, P, N)
    float* __restrict__ Beta)          // (T, N)
{
    const int tid = blockIdx.x * blockDim.x + threadIdx.x;
    const int n = tid & (N - 1);
    const int seq = tid >> 10;          // 0..12
    if (seq > P) return;

    float a[P];
    const float* arow = ar + n * P;
#pragma unroll
    for (int j = 0; j < P; ++j) a[j] = arow[j];

    const bool is_beta = (seq == P);
    const float bs = is_beta ? bias[n] : 0.0f;

    // Scatter-form accumulators (all indices compile-time constant).
    float acc[P];
#pragma unroll
    for (int s = 0; s < P; ++s) acc[s] = bs;

    // History = unit impulse at position seq (zero for the Beta sequence).
#pragma unroll
    for (int i = 0; i < P; ++i) {
        const float hv = (i == seq) ? 1.0f : 0.0f;
#pragma unroll
        for (int t = 0; t <= i; ++t)
            acc[t] = fmaf(a[i - t], hv, acc[t]);
    }

    float* obase = is_beta ? (Beta + n) : (W + (size_t)seq * N + n);
    const size_t ostride = is_beta ? (size_t)N : (size_t)P * N;

#pragma unroll 1
    for (int tt = 0; tt < T; tt += P) {
#pragma unroll
        for (int k = 0; k < P; ++k) {
            const float pred = acc[k];
            obase[(size_t)(tt + k) * ostride] = pred;
            acc[k] = fmaf(a[0], pred, bs);
#pragma unroll
            for (int d = 1; d < P; ++d)
                acc[(k + d) % P] = fmaf(a[P - d], pred, acc[(k + d) % P]);
        }
    }
}

// ---------------- K2: apply -----------------
// out[b,t,n] = Beta[t,n] + sum_j W[t,j,n] * x[b, T-P+j, n]
// Block: 256 lanes = 256 consecutive n. Each thread: BCxTC outputs for its n.
__global__ __launch_bounds__(256) void ar_apply_kernel(
    const float* __restrict__ x,       // (B, T, N)
    const float* __restrict__ W,       // (T, P, N)
    const float* __restrict__ Beta,    // (T, N)
    float* __restrict__ out)           // (B, T, N)
{
    const int bid = blockIdx.x;
    const int nt = bid & 3;                          // N/256 = 4
    const int tt = (bid >> 2) % (T / TC);            // 36
    const int bt = bid / (4 * (T / TC));             // 8
    const int n = nt * 256 + threadIdx.x;
    const int t0 = tt * TC;
    const int b0 = bt * BC;

    // Load the BC history windows for this n (coalesced across lanes).
    float xw[BC][P];
#pragma unroll
    for (int i = 0; i < BC; ++i) {
        const float* xb = x + ((size_t)(b0 + i) * T + (T - P)) * N + n;
#pragma unroll
        for (int j = 0; j < P; ++j)
            xw[i][j] = xb[(size_t)j * N];
    }

#pragma unroll 2
    for (int t = 0; t < TC; ++t) {
        float w[P];
        const float* wrow = W + (size_t)(t0 + t) * P * N + n;
#pragma unroll
        for (int j = 0; j < P; ++j) w[j] = wrow[(size_t)j * N];
        const float bb = Beta[(size_t)(t0 + t) * N + n];
#pragma unroll
        for (int i = 0; i < BC; ++i) {
            float acc = bb;
#pragma unroll
            for (int j = 0; j < P; ++j)
                acc = fmaf(w[j], xw[i][j], acc);
            out[((size_t)(b0 + i) * T + (t0 + t)) * N + n] = acc;
        }
    }
}

// ---------------- fallback (round-2 kernel) ----------------
__global__ __launch_bounds__(256) void ar_model_kernel(
    const float* __restrict__ x, const float* __restrict__ ar,
    const float* __restrict__ bias, float* __restrict__ out)
{
    const int tid = blockIdx.x * blockDim.x + threadIdx.x;
    const int n = tid & (N - 1);
    const int b = tid >> 10;
    if (b >= B) return;
    float a[P];
    const float* arow = ar + n * P;
#pragma unroll
    for (int j = 0; j < P; ++j) a[j] = arow[j];
    const float bs = bias[n];
    float acc[P];
#pragma unroll
    for (int s = 0; s < P; ++s) acc[s] = bs;
    const float* xb = x + (size_t)b * T * N + (size_t)(T - P) * N + n;
#pragma unroll
    for (int i = 0; i < P; ++i) {
        const float hv = xb[(size_t)i * N];
#pragma unroll
        for (int t = 0; t <= i; ++t)
            acc[t] = fmaf(a[i - t], hv, acc[t]);
    }
    float* ob = out + (size_t)b * T * N + n;
#pragma unroll 1
    for (int tt = 0; tt < T; tt += P) {
#pragma unroll
        for (int k = 0; k < P; ++k) {
            const float pred = acc[k];
            ob[(size_t)(tt + k) * N] = pred;
            acc[k] = fmaf(a[0], pred, bs);
#pragma unroll
            for (int d = 1; d < P; ++d)
                acc[(k + d) % P] = fmaf(a[P - d], pred, acc[(k + d) % P]);
        }
    }
}

extern "C" void kernel_launch(void* const* d_in, const int* in_sizes, int n_in,
                              void* d_out, int out_size, void* d_ws, size_t ws_size,
                              hipStream_t stream) {
    const float* x    = (const float*)d_in[0];   // (B,T,N,1) fp32
    const float* ar   = (const float*)d_in[1];   // (N,P) fp32
    const float* bias = (const float*)d_in[2];   // (N,) fp32
    float* out = (float*)d_out;                  // (B,T,N,1) fp32

    const size_t w_elems = (size_t)T * P * N;        // 3,538,944
    const size_t beta_elems = (size_t)T * N;         // 294,912
    const size_t need = (w_elems + beta_elems) * sizeof(float);  // ~14.6 MB

    if (ws_size >= need) {
        float* W = (float*)d_ws;
        float* Beta = W + w_elems;
        // K1: 13 sequences x 1024 n = 13312 threads = 52 blocks.
        ar_propagate_kernel<<<(13 * N) / 256, 256, 0, stream>>>(ar, bias, W, Beta);
        // K2: (N/256) * (T/TC) * (B/BC) = 4*36*8 = 1152 blocks.
        ar_apply_kernel<<<4 * (T / TC) * (B / BC), 256, 0, stream>>>(x, W, Beta, out);
    } else {
        const int total = B * N;
        ar_model_kernel<<<(total + 255) / 256, 256, 0, stream>>>(x, ar, bias, out);
    }
}

// Round 5
// 135.708 us; speedup vs baseline: 1.0477x; 1.0477x over previous
//
#include <hip/hip_runtime.h>

// AR(12) self-feeding recurrence, checkpointed two-pass.
//
// Diagnosis (R2-R4): per-wave serial store streams at low occupancy are
// in-flight-limited (~8 outstanding stores/wave @ ~1us ack latency =>
// ~7.7 GB/s/CU). The monolithic kernel (4 waves/CU, 288 stores/wave) hits
// ~2 TB/s chip write; harness fills at high occupancy hit 6.6 TB/s.
//
// Pass 1: per (b,n) run the scatter recurrence t=0..239, but store only the
//         5 checkpoint windows (preds t in [48c-12, 48c), c=1..5) as float4s.
// Pass 2: per (b,n,chunk c=0..5): load window (x for c=0, ws otherwise),
//         run 48 scatter steps, store 48 preds. 24 waves/CU => write-BW bound.
// Accumulation order identical to the monolithic kernel => bit-identical.

constexpr int B = 64;
constexpr int T = 288;
constexpr int N = 1024;
constexpr int P = 12;
constexpr int CHUNK = 48;                 // 6 chunks of 48 = 288
constexpr int NCHUNK = T / CHUNK;         // 6
constexpr int NCKPT = NCHUNK - 1;         // 5 checkpoint windows

// Scatter one history value hv (logical position i in the P-window) into the
// triangular prologue accumulators.
#define SCATTER_PROLOGUE(acc, a, hv, i)                                        \
  _Pragma("unroll") for (int _t = 0; _t <= (i); ++_t)                          \
      acc[_t] = fmaf(a[(i) - _t], (hv), acc[_t]);

// ---------------- Pass 1: checkpoints ----------------
__global__ __launch_bounds__(256) void ar_ckpt_kernel(
    const float* __restrict__ x,        // (B, T, N)
    const float* __restrict__ ar,       // (N, P)
    const float* __restrict__ bias,     // (N,)
    float* __restrict__ ws)             // (NCKPT, B*N, P)
{
    const int tid = blockIdx.x * blockDim.x + threadIdx.x;   // bn index
    const int n = tid & (N - 1);
    const int b = tid >> 10;
    if (b >= B) return;

    float a[P];
    const float* arow = ar + n * P;
#pragma unroll
    for (int j = 0; j < P; ++j) a[j] = arow[j];
    const float bs = bias[n];

    float acc[P];
#pragma unroll
    for (int s = 0; s < P; ++s) acc[s] = bs;

    const float* xb = x + (size_t)b * T * N + (size_t)(T - P) * N + n;
#pragma unroll
    for (int i = 0; i < P; ++i) {
        const float hv = xb[(size_t)i * N];
        SCATTER_PROLOGUE(acc, a, hv, i)
    }

    // Run t = 0..239; at tt%48==36 the block [tt, tt+12) is the window that
    // seeds chunk tt/48 + 1. Store it as 3x float4 (48B per (b,n), aligned).
#pragma unroll 1
    for (int tt = 0; tt < T - CHUNK; tt += P) {
        float pr[P];
#pragma unroll
        for (int k = 0; k < P; ++k) {
            const float pred = acc[k];
            pr[k] = pred;
            acc[k] = fmaf(a[0], pred, bs);
#pragma unroll
            for (int d = 1; d < P; ++d)
                acc[(k + d) % P] = fmaf(a[P - d], pred, acc[(k + d) % P]);
        }
        if ((tt % CHUNK) == CHUNK - P) {
            const int c = tt / CHUNK;                  // 0..4
            float4* dst = (float4*)(ws + ((size_t)c * B * N + tid) * P);
            dst[0] = make_float4(pr[0], pr[1], pr[2], pr[3]);
            dst[1] = make_float4(pr[4], pr[5], pr[6], pr[7]);
            dst[2] = make_float4(pr[8], pr[9], pr[10], pr[11]);
        }
    }
}

// ---------------- Pass 2: chunks ----------------
__global__ __launch_bounds__(256) void ar_chunk_kernel(
    const float* __restrict__ x,        // (B, T, N)
    const float* __restrict__ ar,       // (N, P)
    const float* __restrict__ bias,     // (N,)
    const float* __restrict__ ws,       // (NCKPT, B*N, P)
    float* __restrict__ out)            // (B, T, N)
{
    const int tid = blockIdx.x * blockDim.x + threadIdx.x;   // (c, b, n)
    const int n = tid & (N - 1);
    const int bn = tid & (B * N - 1);
    const int b = (tid >> 10) & (B - 1);
    const int c = tid / (B * N);                              // 0..5
    if (c >= NCHUNK) return;

    float a[P];
    const float* arow = ar + n * P;
#pragma unroll
    for (int j = 0; j < P; ++j) a[j] = arow[j];
    const float bs = bias[n];

    float acc[P];
#pragma unroll
    for (int s = 0; s < P; ++s) acc[s] = bs;

    if (c == 0) {
        const float* xb = x + (size_t)b * T * N + (size_t)(T - P) * N + n;
#pragma unroll
        for (int i = 0; i < P; ++i) {
            const float hv = xb[(size_t)i * N];
            SCATTER_PROLOGUE(acc, a, hv, i)
        }
    } else {
        const float4* src =
            (const float4*)(ws + ((size_t)(c - 1) * B * N + bn) * P);
        const float4 v0 = src[0], v1 = src[1], v2 = src[2];
        const float hw[P] = {v0.x, v0.y, v0.z, v0.w, v1.x, v1.y,
                             v1.z, v1.w, v2.x, v2.y, v2.z, v2.w};
#pragma unroll
        for (int i = 0; i < P; ++i) {
            const float hv = hw[i];
            SCATTER_PROLOGUE(acc, a, hv, i)
        }
    }

    float* ob = out + (size_t)b * T * N + (size_t)c * CHUNK * N + n;
#pragma unroll 1
    for (int tt = 0; tt < CHUNK; tt += P) {
#pragma unroll
        for (int k = 0; k < P; ++k) {
            const float pred = acc[k];
            ob[(size_t)(tt + k) * N] = pred;       // coalesced 256B/wave
            acc[k] = fmaf(a[0], pred, bs);
#pragma unroll
            for (int d = 1; d < P; ++d)
                acc[(k + d) % P] = fmaf(a[P - d], pred, acc[(k + d) % P]);
        }
    }
}

// ---------------- fallback (verified round-2/3 kernel) ----------------
__global__ __launch_bounds__(256) void ar_model_kernel(
    const float* __restrict__ x, const float* __restrict__ ar,
    const float* __restrict__ bias, float* __restrict__ out)
{
    const int tid = blockIdx.x * blockDim.x + threadIdx.x;
    const int n = tid & (N - 1);
    const int b = tid >> 10;
    if (b >= B) return;
    float a[P];
    const float* arow = ar + n * P;
#pragma unroll
    for (int j = 0; j < P; ++j) a[j] = arow[j];
    const float bs = bias[n];
    float acc[P];
#pragma unroll
    for (int s = 0; s < P; ++s) acc[s] = bs;
    const float* xb = x + (size_t)b * T * N + (size_t)(T - P) * N + n;
#pragma unroll
    for (int i = 0; i < P; ++i) {
        const float hv = xb[(size_t)i * N];
        SCATTER_PROLOGUE(acc, a, hv, i)
    }
    float* ob = out + (size_t)b * T * N + n;
#pragma unroll 1
    for (int tt = 0; tt < T; tt += P) {
#pragma unroll
        for (int k = 0; k < P; ++k) {
            const float pred = acc[k];
            ob[(size_t)(tt + k) * N] = pred;
            acc[k] = fmaf(a[0], pred, bs);
#pragma unroll
            for (int d = 1; d < P; ++d)
                acc[(k + d) % P] = fmaf(a[P - d], pred, acc[(k + d) % P]);
        }
    }
}

extern "C" void kernel_launch(void* const* d_in, const int* in_sizes, int n_in,
                              void* d_out, int out_size, void* d_ws, size_t ws_size,
                              hipStream_t stream) {
    const float* x    = (const float*)d_in[0];   // (B,T,N,1) fp32
    const float* ar   = (const float*)d_in[1];   // (N,P) fp32
    const float* bias = (const float*)d_in[2];   // (N,) fp32
    float* out = (float*)d_out;                  // (B,T,N,1) fp32

    const size_t need = (size_t)NCKPT * B * N * P * sizeof(float);  // 15.7 MB

    if (ws_size >= need) {
        float* ws = (float*)d_ws;
        // Pass 1: one thread per (b,n) -> 256 blocks.
        ar_ckpt_kernel<<<(B * N) / 256, 256, 0, stream>>>(x, ar, bias, ws);
        // Pass 2: one thread per (b,n,chunk) -> 1536 blocks, 24 waves/CU.
        ar_chunk_kernel<<<(B * N * NCHUNK) / 256, 256, 0, stream>>>(
            x, ar, bias, ws, out);
    } else {
        ar_model_kernel<<<(B * N) / 256, 256, 0, stream>>>(x, ar, bias, out);
    }
}

// Round 6
// 126.363 us; speedup vs baseline: 1.1252x; 1.0740x over previous
//
#include <hip/hip_runtime.h>

// AR(12) self-feeding recurrence — single kernel, redundant-compute chunking.
//
// R4/R5 lesson: multi-pass (workspace) variants each ADDED their own kernel
// cost; extra store-TLP in a second pass did not beat the monolithic. This
// round tests store-parallelism directly with zero extra passes: thread
// (b, n, c) replays the recurrence from t=0 (pure-VALU, no stores — the whole
// monolithic compute is only ~3 us of FMA issue) and stores ONLY chunk c
// (72 timesteps). 4x concurrent store streams, one launch, no workspace,
// accumulation order identical to the monolithic kernel => bit-identical.
//
// Decision rule: dur_us ~95-102 => store-parallelism was the limiter (keep).
// dur_us ~116-123 => monolithic was already at the write-BW floor; the rest
// of dur_us is fixed harness fill/restore traffic => roofline.

constexpr int B = 64;
constexpr int T = 288;
constexpr int N = 1024;
constexpr int P = 12;
constexpr int CHUNK = 72;               // 288 = 4 * 72, 72 % 12 == 0
constexpr int NCHUNK = T / CHUNK;       // 4

__global__ __launch_bounds__(256) void ar_chunked_kernel(
    const float* __restrict__ x,        // (B, T, N, 1)
    const float* __restrict__ ar,       // (N, P)
    const float* __restrict__ bias,     // (N,)
    float* __restrict__ out)            // (B, T, N, 1)
{
    const int tid = blockIdx.x * blockDim.x + threadIdx.x;  // c * 2^16 + b*N + n
    const int n = tid & (N - 1);
    const int b = (tid >> 10) & (B - 1);
    const int c = tid >> 16;            // block-uniform (B*N = 65536, 256 | 65536)

    // Per-node AR coefficients.
    float a[P];
    const float* arow = ar + n * P;
#pragma unroll
    for (int j = 0; j < P; ++j) a[j] = arow[j];
    const float bs = bias[n];

    // Scatter-form accumulators; acc[t % P] accumulates pred_t.
    float acc[P];
#pragma unroll
    for (int s = 0; s < P; ++s) acc[s] = bs;

    // Triangular prologue from the last P input timesteps (coalesced loads).
    const float* xb = x + (size_t)b * T * N + (size_t)(T - P) * N + n;
#pragma unroll
    for (int i = 0; i < P; ++i) {
        const float hv = xb[(size_t)i * N];
#pragma unroll
        for (int t = 0; t <= i; ++t)
            acc[t] = fmaf(a[i - t], hv, acc[t]);
    }

    // Phase 1: replay steps [0, c*CHUNK) without storing (pure VALU; the
    // 12-step inner loop is fully unrolled so all indices are constants).
    const int skip = c * CHUNK;
#pragma unroll 1
    for (int tt = 0; tt < skip; tt += P) {
#pragma unroll
        for (int k = 0; k < P; ++k) {
            const float pred = acc[k];
            acc[k] = fmaf(a[0], pred, bs);
#pragma unroll
            for (int d = 1; d < P; ++d)
                acc[(k + d) % P] = fmaf(a[P - d], pred, acc[(k + d) % P]);
        }
    }

    // Phase 2: my chunk — compute and store 72 timesteps (256B/wave stores).
    float* ob = out + (size_t)b * T * N + (size_t)skip * N + n;
#pragma unroll 1
    for (int tt = 0; tt < CHUNK; tt += P) {
#pragma unroll
        for (int k = 0; k < P; ++k) {
            const float pred = acc[k];
            ob[(size_t)(tt + k) * N] = pred;
            acc[k] = fmaf(a[0], pred, bs);
#pragma unroll
            for (int d = 1; d < P; ++d)
                acc[(k + d) % P] = fmaf(a[P - d], pred, acc[(k + d) % P]);
        }
    }
}

extern "C" void kernel_launch(void* const* d_in, const int* in_sizes, int n_in,
                              void* d_out, int out_size, void* d_ws, size_t ws_size,
                              hipStream_t stream) {
    const float* x    = (const float*)d_in[0];   // (B,T,N,1) fp32
    const float* ar   = (const float*)d_in[1];   // (N,P) fp32
    const float* bias = (const float*)d_in[2];   // (N,) fp32
    float* out = (float*)d_out;                  // (B,T,N,1) fp32

    // One thread per (b, n, chunk): 4 * 65536 threads = 1024 blocks,
    // ~16 waves/CU — 4x the concurrent store streams of the monolithic.
    const int total = B * N * NCHUNK;
    ar_chunked_kernel<<<total / 256, 256, 0, stream>>>(x, ar, bias, out);
}